// Round 14
// baseline (34938.849 us; speedup 1.0000x reference)
//
#include <hip/hip_runtime.h>
#include <hip/hip_bf16.h>
#include <math.h>

// Multilayer GRU: B=32, S=512, H=1024, L=3, O=1024.
// v14: v13 (32-col blocks, packed activations, halved broadcast traffic)
// with the publish-width bug fixed: a 32-col block publishes a FULL 1KB
// packed tile -> all 64 lanes store (v13 kept v12's lane<32 guard from the
// 16-col half-tile era, so cols 16..31 of every chunk were never written).

#define BB 32
#define SS 512
#define HH 1024
#define LL 3
#define OO 1024
#define SH (SS*HH)
#define NBL 32

typedef __attribute__((ext_vector_type(8))) short short8;
typedef __attribute__((ext_vector_type(4))) float float4v;
typedef unsigned long long u64;
typedef unsigned int u32;
typedef unsigned short u16;

__device__ __forceinline__ u16 f2bf(float f) {
  union { float f; u32 u; } v; v.f = f;
  return (u16)((v.u + 0x7FFFu + ((v.u >> 16) & 1u)) >> 16);
}

__global__ void convert_bf16(const float* __restrict__ src,
                             u16* __restrict__ dst, int n) {
  int stride = gridDim.x * blockDim.x;
  for (int i = blockIdx.x * blockDim.x + threadIdx.x; i < n; i += stride)
    dst[i] = f2bf(src[i]);
}

// Pack W[nmat][1024][1024] into MFMA B-fragment stream
__global__ void pack_w(const float* __restrict__ src, u16* __restrict__ dst,
                       int nmat) {
  int stride = gridDim.x * blockDim.x;
  int total = nmat * 1048576;
  for (int i = blockIdx.x * blockDim.x + threadIdx.x; i < total; i += stride) {
    int m = i >> 20, e = i & 1048575;
    int row = e >> 10, k = e & 1023;
    int lane = ((k >> 3) & 3) * 16 + (row & 15);
    int di = ((row >> 4) * 32 + (k >> 5)) * 512 + lane * 8 + (k & 7);
    dst[m * 1048576 + di] = f2bf(src[i]);
  }
}

// x[B,S,H] fp32 -> packed per-t activation tiles
__global__ void pack_x(const float* __restrict__ x, u16* __restrict__ dst) {
  int stride = gridDim.x * blockDim.x;
  for (int d = blockIdx.x * blockDim.x + threadIdx.x; d < SS * 32768; d += stride) {
    int t = d >> 15, e = d & 32767;
    int rt = e >> 14, ks = (e >> 9) & 31, lane = (e >> 3) & 63, j = e & 7;
    int b = rt * 16 + (lane & 15), c = ks * 32 + ((lane >> 4) << 3) + j;
    dst[d] = f2bf(x[(size_t)b * SH + (size_t)t * HH + c]);
  }
}

// h0[B, L, H] fp32 -> slot 0 of each layer chain (packed)
__global__ void pack_h0(const float* __restrict__ h0, u16* __restrict__ y0,
                        u16* __restrict__ y1, u16* __restrict__ y2) {
  int i = blockIdx.x * 256 + threadIdx.x;   // 98304
  int l = i >> 15, e = i & 32767;
  int rt = e >> 14, ks = (e >> 9) & 31, lane = (e >> 3) & 63, j = e & 7;
  int b = rt * 16 + (lane & 15), c = ks * 32 + ((lane >> 4) << 3) + j;
  u16 v = f2bf(h0[b * (LL * HH) + l * HH + c]);
  u16* dst = (l == 0) ? y0 : ((l == 1) ? y1 : y2);
  dst[e] = v;
}

// ---- access primitives ----------------------------------------------------
__device__ __forceinline__ short8 coh16(const u16* p) {
  const u64* q = (const u64*)p;
  union { u64 q[2]; short8 v; } u;
  u.q[0] = __hip_atomic_load(q,     __ATOMIC_RELAXED, __HIP_MEMORY_SCOPE_AGENT);
  u.q[1] = __hip_atomic_load(q + 1, __ATOMIC_RELAXED, __HIP_MEMORY_SCOPE_AGENT);
  return u.v;
}
__device__ __forceinline__ void coh_store16(u16* p, short8 v) {
  asm volatile("global_store_dwordx4 %0, %1, off sc0 sc1"
               :: "v"(p), "v"(v) : "memory");
}
__device__ __forceinline__ void coh_store_u32(int* p, int v) {
  asm volatile("global_store_dword %0, %1, off sc0 sc1"
               :: "v"(p), "v"(v) : "memory");
}
// poll 64 flags (1/lane) until all >= tgt
__device__ __forceinline__ void poll64(const int* base, int lane, int tgt) {
  int f = __hip_atomic_load(base + lane, __ATOMIC_RELAXED,
                            __HIP_MEMORY_SCOPE_AGENT);
  while (__any(f < tgt)) {
    __builtin_amdgcn_s_sleep(1);
    f = __hip_atomic_load(base + lane, __ATOMIC_RELAXED,
                          __HIP_MEMORY_SCOPE_AGENT);
  }
}

#define MFMA16(a, b, c) __builtin_amdgcn_mfma_f32_16x16x32_bf16(a, b, c, 0, 0, 0)

__launch_bounds__(256, 1)
__global__ void gru_pipe(
    const u16* __restrict__ xpk0,
    u16* __restrict__ ypk0, u16* __restrict__ ypk1, u16* __restrict__ ypk2,
    const u16* __restrict__ Pzh, const u16* __restrict__ Pzx,
    const u16* __restrict__ Prh, const u16* __restrict__ Prx,
    const u16* __restrict__ Pgh, const u16* __restrict__ Pgx,
    const float* __restrict__ bz, const float* __restrict__ br,
    const float* __restrict__ bg, const float* __restrict__ h0,
    u16* __restrict__ rhA, float* __restrict__ hid,
    int* __restrict__ flagsD, int* __restrict__ flagsP) {
  __shared__ float redz[2][4][2][64], redr[2][4][2][64], redg[2][4][2][64];
  __shared__ __align__(16) u16 pubP[2][512];      // per-mt packed publish buf

  const int grp = blockIdx.x >> 5;        // layer 0..2
  const int blk = blockIdx.x & 31;        // 32-col tile (= packed ks index)
  const int tid = threadIdx.x;
  const int lane = tid & 63;
  const int wave = tid >> 6;
  const int mt = wave & 1;                // M-tile: rows 0-15 / 16-31
  const int kh = wave >> 1;               // phase1 side: 0=h, 1=x
  const int fcol = lane & 15, kg = lane >> 4;
  const int crow0 = mt * 16 + kg * 4;
  const int colA = blk * 32 + fcol;       // s=0 col; s=1 -> +16

  u16* ypkl       = (grp == 0) ? ypk0 : ((grp == 1) ? ypk1 : ypk2);
  const u16* ypkp = (grp == 1) ? ypk0 : ypk1;
  const bool circ = (grp < 2);
  const size_t lw = (size_t)grp * 1048576;
  const u16 *w1z[2], *w1r[2], *wgx[2], *wgh[2];
#pragma unroll
  for (int s = 0; s < 2; ++s) {
    const int nb = blk * 2 + s;
    w1z[s] = (kh ? Pzx : Pzh) + lw + nb * 16384 + lane * 8;
    w1r[s] = (kh ? Prx : Prh) + lw + nb * 16384 + lane * 8;
    wgx[s] = Pgx + lw + nb * 16384 + lane * 8;
    wgh[s] = Pgh + lw + nb * 16384 + lane * 8;
  }
  u16* rhl = rhA + grp * 32768;
  int* selfD = flagsD + (grp + 1) * 64;
  int* prodD = flagsD + grp * 64;
  int* consD = flagsD + (grp + 2) * 64;   // valid only grp<2
  int* selfP = flagsP + grp * 64;

  float hreg[2][4], zreg[2][4];
  float bzv[2] = {0, 0}, brv[2] = {0, 0}, bgv[2] = {0, 0};
  if (kh == 0) {
#pragma unroll
    for (int s = 0; s < 2; ++s) {
#pragma unroll
      for (int q = 0; q < 4; ++q)
        hreg[s][q] = h0[(crow0 + q) * (LL * HH) + grp * HH + colA + s * 16];
      bzv[s] = bz[grp * HH + colA + s * 16];
      brv[s] = br[grp * HH + colA + s * 16];
      bgv[s] = bg[grp * HH + colA + s * 16];
    }
  }

  for (int t = 0; t < SS; ++t) {
    const int hslot = circ ? (t & 127) : t;
    const int wslot = circ ? ((t + 1) & 127) : (t + 1);

    // ---- phase-1 gate (per-wave) ----------------------------------------
    if (kh == 0) {
      poll64(selfD, lane, t);                         // own-layer h RAW/WAR
      if (circ && t >= 128) poll64(consD, lane, t - 127);  // chain WAR
    } else if (grp != 0) {
      poll64(prodD, lane, t + 1);                     // producer y[t] ready
    }

    float4v az[2], ar[2], ag[2];
#pragma unroll
    for (int s = 0; s < 2; ++s) {
      az[s] = (float4v){0,0,0,0}; ar[s] = (float4v){0,0,0,0};
      ag[s] = (float4v){0,0,0,0};
    }
    short8 cf[16];

    const u16* Ab = (kh == 0)
        ? (ypkl + (size_t)hslot * 32768 + mt * 16384 + lane * 8)
        : ((grp != 0)
            ? (ypkp + (size_t)((t + 1) & 127) * 32768 + mt * 16384 + lane * 8)
            : (xpk0 + (size_t)t * 32768 + mt * 16384 + lane * 8));
    const bool Acoh = (kh == 0) || (grp != 0);

#pragma unroll
    for (int c0 = 0; c0 < 32; c0 += 16) {
      if (Acoh) {
#pragma unroll
        for (int k = 0; k < 16; ++k) cf[k] = coh16(Ab + (c0 + k) * 512);
      } else {
#pragma unroll
        for (int k = 0; k < 16; ++k) cf[k] = *(const short8*)(Ab + (c0 + k) * 512);
      }
#pragma unroll
      for (int k = 0; k < 16; ++k) {
        const int ks = c0 + k;
        az[0] = MFMA16(cf[k], *(const short8*)(w1z[0] + ks * 512), az[0]);
        az[1] = MFMA16(cf[k], *(const short8*)(w1z[1] + ks * 512), az[1]);
        ar[0] = MFMA16(cf[k], *(const short8*)(w1r[0] + ks * 512), ar[0]);
        ar[1] = MFMA16(cf[k], *(const short8*)(w1r[1] + ks * 512), ar[1]);
        if (kh) {
          ag[0] = MFMA16(cf[k], *(const short8*)(wgx[0] + ks * 512), ag[0]);
          ag[1] = MFMA16(cf[k], *(const short8*)(wgx[1] + ks * 512), ag[1]);
        }
      }
    }
    if (kh) {
#pragma unroll
      for (int s = 0; s < 2; ++s)
#pragma unroll
        for (int q = 0; q < 4; ++q) {
          redz[s][q][mt][lane] = az[s][q];
          redr[s][q][mt][lane] = ar[s][q];
        }
    }
    __syncthreads();

    if (kh == 0) {
      // finalize z,r; packed-publish r*h (full 1KB tile, all 64 lanes)
#pragma unroll
      for (int s = 0; s < 2; ++s)
#pragma unroll
        for (int q = 0; q < 4; ++q) {
          float pz = az[s][q] + redz[s][q][mt][lane] + bzv[s];
          float pr = ar[s][q] + redr[s][q][mt][lane] + brv[s];
          zreg[s][q] = 1.f / (1.f + expf(-pz));
          float rv = 1.f / (1.f + expf(-pr));
          pubP[mt][((s * 2 + (fcol >> 3)) * 16 + kg * 4 + q) * 8 + (fcol & 7)] =
              f2bf(rv * hreg[s][q]);
        }
      asm volatile("s_waitcnt lgkmcnt(0)" ::: "memory");
      __builtin_amdgcn_sched_barrier(0);
      {
        short8 v = *(const short8*)(pubP[mt] + lane * 8);
        coh_store16(rhl + (mt * 32 + blk) * 512 + lane * 8, v);
      }
      asm volatile("s_waitcnt vmcnt(0)" ::: "memory");
      if (lane == 0) coh_store_u32(selfP + blk * 2 + mt, t + 1);
    }

    // ---- phase-2 gate: all r*h published
    poll64(selfP, lane, t + 1);

    // rh frags (packed): 16 chunks per wave (K split by kh)
    {
      const u16* rbase = rhl + mt * 16384 + kh * 8192 + lane * 8;
#pragma unroll
      for (int k = 0; k < 16; ++k) cf[k] = coh16(rbase + k * 512);
#pragma unroll
      for (int k = 0; k < 16; ++k) {
        const int ks = kh * 16 + k;
        ag[0] = MFMA16(cf[k], *(const short8*)(wgh[0] + ks * 512), ag[0]);
        ag[1] = MFMA16(cf[k], *(const short8*)(wgh[1] + ks * 512), ag[1]);
      }
    }
    if (kh) {
#pragma unroll
      for (int s = 0; s < 2; ++s)
#pragma unroll
        for (int q = 0; q < 4; ++q) redg[s][q][mt][lane] = ag[s][q];
    }
    __syncthreads();

    if (kh == 0) {
#pragma unroll
      for (int s = 0; s < 2; ++s)
#pragma unroll
        for (int q = 0; q < 4; ++q) {
          float pg = ag[s][q] + redg[s][q][mt][lane] + bgv[s];
          float gv = tanhf(pg);
          float hn = zreg[s][q] * hreg[s][q] + (1.f - zreg[s][q]) * gv;
          hreg[s][q] = hn;
          pubP[mt][((s * 2 + (fcol >> 3)) * 16 + kg * 4 + q) * 8 + (fcol & 7)] =
              f2bf(hn);
          if (t == SS - 1)
            hid[(crow0 + q) * (LL * HH) + grp * HH + colA + s * 16] = hn;
        }
      asm volatile("s_waitcnt lgkmcnt(0)" ::: "memory");
      __builtin_amdgcn_sched_barrier(0);
      {
        short8 v = *(const short8*)(pubP[mt] + lane * 8);
        coh_store16(ypkl + (size_t)wslot * 32768 + (mt * 32 + blk) * 512 + lane * 8, v);
      }
      asm volatile("s_waitcnt vmcnt(0)" ::: "memory");
      if (lane == 0) coh_store_u32(selfD + blk * 2 + mt, t + 1);
    }
  }
}

// layer_output[b,s,:] = y2[b][s][:] @ Wo^T + bo, A read in packed form
__launch_bounds__(64)
__global__ void out_gemm(const u16* __restrict__ ypk2, const u16* __restrict__ W,
                         const float* __restrict__ bo, float* __restrict__ C) {
  const int lane = threadIdx.x;
  const int nt4 = blockIdx.x & 15;
  const int sb = blockIdx.x >> 4;   // 0..1023
  const int s = sb >> 1, bt = sb & 1;
  const int n0 = nt4 * 64;
  const int fcol = lane & 15, kg = lane >> 4;
  const u16* Abase = ypk2 + (size_t)(s + 1) * 32768 + bt * 16384 + lane * 8;
  float4v acc[4];
#pragma unroll
  for (int j = 0; j < 4; ++j) acc[j] = (float4v){0, 0, 0, 0};

  for (int ks = 0; ks < 32; ++ks) {
    short8 a = *(const short8*)(Abase + ks * 512);
#pragma unroll
    for (int j = 0; j < 4; ++j) {
      short8 b = *(const short8*)(W + (size_t)(n0 + j * 16 + fcol) * HH + ks * 32 + kg * 8);
      acc[j] = MFMA16(a, b, acc[j]);
    }
  }
#pragma unroll
  for (int j = 0; j < 4; ++j)
#pragma unroll
    for (int q = 0; q < 4; ++q) {
      int b = bt * 16 + kg * 4 + q;
      int col = n0 + j * 16 + fcol;
      C[((size_t)b * SS + s) * OO + col] = acc[j][q] + bo[col];
    }
}

extern "C" void kernel_launch(void* const* d_in, const int* in_sizes, int n_in,
                              void* d_out, int out_size, void* d_ws, size_t ws_size,
                              hipStream_t stream) {
  (void)in_sizes; (void)n_in; (void)out_size; (void)ws_size;

  const float* x   = (const float*)d_in[0];
  const float* h0  = (const float*)d_in[1];
  const float* Wzx = (const float*)d_in[2];
  const float* bz  = (const float*)d_in[3];
  const float* Wzh = (const float*)d_in[4];
  const float* Wrx = (const float*)d_in[5];
  const float* br  = (const float*)d_in[6];
  const float* Wrh = (const float*)d_in[7];
  const float* Wgx = (const float*)d_in[8];
  const float* bg  = (const float*)d_in[9];
  const float* Wgh = (const float*)d_in[10];
  const float* Wo  = (const float*)d_in[11];
  const float* bo  = (const float*)d_in[12];
  float* out = (float*)d_out;

  // ws layout (~124 MB)
  u16* Pzh = (u16*)d_ws;
  u16* Pzx = Pzh + 3145728;
  u16* Prh = Pzx + 3145728;
  u16* Prx = Prh + 3145728;
  u16* Pgh = Prx + 3145728;
  u16* Pgx = Pgh + 3145728;
  u16* Wob = Pgx + 3145728;                 // 1M elems
  u16* xpk0 = Wob + 1048576;                // [512][32768]
  u16* ypk0 = xpk0 + 16777216;              // [128][32768] circular
  u16* ypk1 = ypk0 + 128 * 32768;           // [128][32768] circular
  u16* ypk2 = ypk1 + 128 * 32768;           // [513][32768]
  u16* rhA  = ypk2 + 513 * 32768;           // [3][32768]
  int* flagsD = (int*)(rhA + 3 * 32768);    // 4 groups x 64
  int* flagsP = flagsD + 256;               // 3 groups x 64

  hipMemsetAsync(flagsD, 0, (256 + 192) * sizeof(int), stream);

  pack_w<<<3072, 256, 0, stream>>>(Wzh, Pzh, 3);
  pack_w<<<3072, 256, 0, stream>>>(Wzx, Pzx, 3);
  pack_w<<<3072, 256, 0, stream>>>(Wrh, Prh, 3);
  pack_w<<<3072, 256, 0, stream>>>(Wrx, Prx, 3);
  pack_w<<<3072, 256, 0, stream>>>(Wgh, Pgh, 3);
  pack_w<<<3072, 256, 0, stream>>>(Wgx, Pgx, 3);
  convert_bf16<<<256, 256, 0, stream>>>(Wo, Wob, 1048576);
  pack_x<<<4096, 256, 0, stream>>>(x, xpk0);
  pack_h0<<<384, 256, 0, stream>>>(h0, ypk0, ypk1, ypk2);

  gru_pipe<<<96, 256, 0, stream>>>(
      xpk0, ypk0, ypk1, ypk2,
      Pzh, Pzx, Prh, Prx, Pgh, Pgx,
      bz, br, bg, h0, rhA, out + 16777216, flagsD, flagsP);

  out_gemm<<<16384, 64, 0, stream>>>(ypk2, Wob, bo, out);
}

// Round 15
// 26314.316 us; speedup vs baseline: 1.3278x; 1.3278x over previous
//
#include <hip/hip_runtime.h>
#include <hip/hip_bf16.h>
#include <math.h>

// Multilayer GRU: B=32, S=512, H=1024, L=3, O=1024.
// v15: v12 (best: 16-col blocks, 64/layer, packed activations, LDS h-weights)
// + two latency cuts on the measured serial chain:
//  (1) optimistic execute-and-validate gates: single flag pre-check ->
//      loads+GEMM immediately; commit if pre-check passed (producers flag
//      only after vmcnt-drained publishes; sched_barrier pins check order),
//      else poll + recompute (compute ~0.2us, nearly free).
//  (2) per-mt flags: the two 16-row recurrences are independent; each wave
//      gates on 64 producers (its mt) instead of 128 -> less skew wait.

#define BB 32
#define SS 512
#define HH 1024
#define LL 3
#define OO 1024
#define SH (SS*HH)

typedef __attribute__((ext_vector_type(8))) short short8;
typedef __attribute__((ext_vector_type(4))) float float4v;
typedef unsigned long long u64;
typedef unsigned int u32;
typedef unsigned short u16;

__device__ __forceinline__ u16 f2bf(float f) {
  union { float f; u32 u; } v; v.f = f;
  return (u16)((v.u + 0x7FFFu + ((v.u >> 16) & 1u)) >> 16);
}

__global__ void convert_bf16(const float* __restrict__ src,
                             u16* __restrict__ dst, int n) {
  int stride = gridDim.x * blockDim.x;
  for (int i = blockIdx.x * blockDim.x + threadIdx.x; i < n; i += stride)
    dst[i] = f2bf(src[i]);
}

// Pack W[nmat][1024][1024] into MFMA B-fragment stream
__global__ void pack_w(const float* __restrict__ src, u16* __restrict__ dst,
                       int nmat) {
  int stride = gridDim.x * blockDim.x;
  int total = nmat * 1048576;
  for (int i = blockIdx.x * blockDim.x + threadIdx.x; i < total; i += stride) {
    int m = i >> 20, e = i & 1048575;
    int row = e >> 10, k = e & 1023;
    int lane = ((k >> 3) & 3) * 16 + (row & 15);
    int di = ((row >> 4) * 32 + (k >> 5)) * 512 + lane * 8 + (k & 7);
    dst[m * 1048576 + di] = f2bf(src[i]);
  }
}

// x[B,S,H] fp32 -> packed per-t activation tiles
__global__ void pack_x(const float* __restrict__ x, u16* __restrict__ dst) {
  int stride = gridDim.x * blockDim.x;
  for (int d = blockIdx.x * blockDim.x + threadIdx.x; d < SS * 32768; d += stride) {
    int t = d >> 15, e = d & 32767;
    int rt = e >> 14, ks = (e >> 9) & 31, lane = (e >> 3) & 63, j = e & 7;
    int b = rt * 16 + (lane & 15), c = ks * 32 + ((lane >> 4) << 3) + j;
    dst[d] = f2bf(x[(size_t)b * SH + (size_t)t * HH + c]);
  }
}

// h0[B, L, H] fp32 -> slot 0 of each layer chain (packed)
__global__ void pack_h0(const float* __restrict__ h0, u16* __restrict__ y0,
                        u16* __restrict__ y1, u16* __restrict__ y2) {
  int i = blockIdx.x * 256 + threadIdx.x;   // 98304
  int l = i >> 15, e = i & 32767;
  int rt = e >> 14, ks = (e >> 9) & 31, lane = (e >> 3) & 63, j = e & 7;
  int b = rt * 16 + (lane & 15), c = ks * 32 + ((lane >> 4) << 3) + j;
  u16 v = f2bf(h0[b * (LL * HH) + l * HH + c]);
  u16* dst = (l == 0) ? y0 : ((l == 1) ? y1 : y2);
  dst[e] = v;
}

// ---- access primitives ----------------------------------------------------
__device__ __forceinline__ short8 coh16(const u16* p) {
  const u64* q = (const u64*)p;
  union { u64 q[2]; short8 v; } u;
  u.q[0] = __hip_atomic_load(q,     __ATOMIC_RELAXED, __HIP_MEMORY_SCOPE_AGENT);
  u.q[1] = __hip_atomic_load(q + 1, __ATOMIC_RELAXED, __HIP_MEMORY_SCOPE_AGENT);
  return u.v;
}
__device__ __forceinline__ int aloadi(const int* p) {
  return __hip_atomic_load(p, __ATOMIC_RELAXED, __HIP_MEMORY_SCOPE_AGENT);
}
__device__ __forceinline__ void coh_store16(u16* p, short8 v) {
  asm volatile("global_store_dwordx4 %0, %1, off sc0 sc1"
               :: "v"(p), "v"(v) : "memory");
}
__device__ __forceinline__ void coh_store_u32(int* p, int v) {
  asm volatile("global_store_dword %0, %1, off sc0 sc1"
               :: "v"(p), "v"(v) : "memory");
}
// poll 64 flags (1/lane) until all >= tgt
__device__ __forceinline__ void poll64(const int* base, int lane, int tgt) {
  int f = aloadi(base + lane);
  while (__any(f < tgt)) {
    __builtin_amdgcn_s_sleep(1);
    f = aloadi(base + lane);
  }
}

#define MFMA16(a, b, c) __builtin_amdgcn_mfma_f32_16x16x32_bf16(a, b, c, 0, 0, 0)

__launch_bounds__(256, 1)
__global__ void gru_pipe(
    const u16* __restrict__ xpk0,
    u16* __restrict__ ypk0, u16* __restrict__ ypk1, u16* __restrict__ ypk2,
    const u16* __restrict__ Pzh, const u16* __restrict__ Pzx,
    const u16* __restrict__ Prh, const u16* __restrict__ Prx,
    const u16* __restrict__ Pgh, const u16* __restrict__ Pgx,
    const float* __restrict__ bz, const float* __restrict__ br,
    const float* __restrict__ bg, const float* __restrict__ h0,
    u16* __restrict__ rhA, float* __restrict__ hid,
    int* __restrict__ flagsD, int* __restrict__ flagsP) {
  __shared__ __align__(16) u16 smW[3][16384];     // Wzh, Wrh, Wgh (96 KB)
  __shared__ float redz[4][2][64], redr[4][2][64], redg[4][2][64];
  __shared__ __align__(16) u16 pubP[2][256];      // per-mt packed publish buf

  const int grp = blockIdx.x >> 6;        // layer 0..2
  const int blk = blockIdx.x & 63;        // 16-col tile
  const int tid = threadIdx.x;
  const int lane = tid & 63;
  const int wave = tid >> 6;
  const int mt = wave & 1;                // M-tile: rows 0-15 / 16-31
  const int kh = wave >> 1;               // phase1 side: 0=h, 1=x
  const int fcol = lane & 15, kg = lane >> 4;
  const int crow0 = mt * 16 + kg * 4;
  const int colZ = blk * 16 + fcol;

  u16* ypkl       = (grp == 0) ? ypk0 : ((grp == 1) ? ypk1 : ypk2);
  const u16* ypkp = (grp == 1) ? ypk0 : ypk1;
  const bool circ = (grp < 2);
  const size_t lw = (size_t)grp * 1048576;
  const u16* wZx = Pzx + lw + blk * 16384 + lane * 8;
  const u16* wRx = Prx + lw + blk * 16384 + lane * 8;
  const u16* wGx = Pgx + lw + blk * 16384 + lane * 8;
  u16* rhl = rhA + grp * 32768;
  // per-mt flag banks: [grp][mt*64 + blk]
  int* selfD = flagsD + (grp + 1) * 128 + mt * 64;
  int* prodD = flagsD + grp * 128 + mt * 64;
  int* consD = flagsD + (grp + 2) * 128 + mt * 64;  // valid only grp<2
  int* selfP = flagsP + grp * 128 + mt * 64;

  // ---- stage h-side weight slices into LDS (once) -------------------------
  {
    const u64* g0 = (const u64*)(Pzh + lw + blk * 16384);
    const u64* g1 = (const u64*)(Prh + lw + blk * 16384);
    const u64* g2 = (const u64*)(Pgh + lw + blk * 16384);
    u64* d0 = (u64*)smW[0];
    u64* d1 = (u64*)smW[1];
    u64* d2 = (u64*)smW[2];
#pragma unroll
    for (int j = 0; j < 16; ++j) {
      d0[j * 256 + tid] = g0[j * 256 + tid];
      d1[j * 256 + tid] = g1[j * 256 + tid];
      d2[j * 256 + tid] = g2[j * 256 + tid];
    }
  }
  __syncthreads();
  const u16* lZ = smW[0] + lane * 8;
  const u16* lR = smW[1] + lane * 8;
  const u16* lG = smW[2] + lane * 8;

  float hreg[4] = {0, 0, 0, 0}, zreg[4] = {0, 0, 0, 0};
  float bzv = 0, brv = 0, bgv = 0;
  if (kh == 0) {
#pragma unroll
    for (int q = 0; q < 4; ++q)
      hreg[q] = h0[(crow0 + q) * (LL * HH) + grp * HH + colZ];
    bzv = bz[grp * HH + colZ];
    brv = br[grp * HH + colZ];
    bgv = bg[grp * HH + colZ];
  }

  // publish target within a packed 32-col tile (block owns a 16-col half)
  const int pubOff = (mt * 32 + (blk >> 1)) * 512 + (blk & 1) * 256;

  for (int t = 0; t < SS; ++t) {
    const int hslot = circ ? (t & 127) : t;
    const int wslot = circ ? ((t + 1) & 127) : (t + 1);

    float4v az0 = {0,0,0,0}, az1 = {0,0,0,0};
    float4v ar0 = {0,0,0,0}, ar1 = {0,0,0,0};
    float4v ag0 = {0,0,0,0}, ag1 = {0,0,0,0};
    short8 cf[16];

    // ---- phase 1: optimistic gate + load + GEMM --------------------------
    if (kh == 0) {
      // gate: h[t] rows-mt published; chain WAR if circular
      bool ready;
      {
        int f0 = aloadi(selfD + lane);
        bool r0 = !__any(f0 < t);
        bool r1 = true;
        if (circ && t >= 128) {
          int f1 = aloadi(consD + lane);
          r1 = !__any(f1 < t - 127);
        }
        ready = r0 && r1;
      }
      __builtin_amdgcn_sched_barrier(0);
      const u16* hbase = ypkl + (size_t)hslot * 32768 + mt * 16384 + lane * 8;
      for (int a = 0; a < 2; ++a) {
        az0 = (float4v){0,0,0,0}; az1 = (float4v){0,0,0,0};
        ar0 = (float4v){0,0,0,0}; ar1 = (float4v){0,0,0,0};
#pragma unroll
        for (int c0 = 0; c0 < 32; c0 += 16) {
#pragma unroll
          for (int k = 0; k < 16; ++k) cf[k] = coh16(hbase + (c0 + k) * 512);
#pragma unroll
          for (int k = 0; k < 16; ++k) {
            short8 vz = *(const short8*)(lZ + (c0 + k) * 512);
            short8 vr = *(const short8*)(lR + (c0 + k) * 512);
            if (k & 1) { az1 = MFMA16(cf[k], vz, az1); ar1 = MFMA16(cf[k], vr, ar1); }
            else       { az0 = MFMA16(cf[k], vz, az0); ar0 = MFMA16(cf[k], vr, ar0); }
          }
        }
        if (ready) break;
        poll64(selfD, lane, t);
        if (circ && t >= 128) poll64(consD, lane, t - 127);
        __builtin_amdgcn_sched_barrier(0);
        ready = true;
      }
    } else {
      // x-side: gate on producer (grp>0), layer0 reads static packed x
      bool ready = true;
      if (grp != 0) {
        int f0 = aloadi(prodD + lane);
        ready = !__any(f0 < t + 1);
      }
      __builtin_amdgcn_sched_barrier(0);
      const u16* xbase = (grp == 0)
          ? (xpk0 + (size_t)t * 32768 + mt * 16384 + lane * 8)
          : (ypkp + (size_t)((t + 1) & 127) * 32768 + mt * 16384 + lane * 8);
      for (int a = 0; a < 2; ++a) {
        az0 = (float4v){0,0,0,0}; az1 = (float4v){0,0,0,0};
        ar0 = (float4v){0,0,0,0}; ar1 = (float4v){0,0,0,0};
        ag0 = (float4v){0,0,0,0}; ag1 = (float4v){0,0,0,0};
#pragma unroll
        for (int c0 = 0; c0 < 32; c0 += 16) {
          if (grp != 0) {
#pragma unroll
            for (int k = 0; k < 16; ++k) cf[k] = coh16(xbase + (c0 + k) * 512);
          } else {
#pragma unroll
            for (int k = 0; k < 16; ++k) cf[k] = *(const short8*)(xbase + (c0 + k) * 512);
          }
#pragma unroll
          for (int k = 0; k < 16; ++k) {
            int ks = c0 + k;
            short8 vz = *(const short8*)(wZx + ks * 512);
            short8 vr = *(const short8*)(wRx + ks * 512);
            short8 vg = *(const short8*)(wGx + ks * 512);
            if (k & 1) { az1 = MFMA16(cf[k], vz, az1); ar1 = MFMA16(cf[k], vr, ar1);
                         ag1 = MFMA16(cf[k], vg, ag1); }
            else       { az0 = MFMA16(cf[k], vz, az0); ar0 = MFMA16(cf[k], vr, ar0);
                         ag0 = MFMA16(cf[k], vg, ag0); }
          }
        }
        if (ready) break;
        poll64(prodD, lane, t + 1);
        __builtin_amdgcn_sched_barrier(0);
        ready = true;
      }
#pragma unroll
      for (int q = 0; q < 4; ++q) {
        redz[q][mt][lane] = az0[q] + az1[q];
        redr[q][mt][lane] = ar0[q] + ar1[q];
      }
    }
    __syncthreads();

    if (kh == 0) {
      // finalize z,r; packed-publish r*h (one dwordx4/lane over 32 lanes)
#pragma unroll
      for (int q = 0; q < 4; ++q) {
        float pz = az0[q] + az1[q] + redz[q][mt][lane] + bzv;
        float pr = ar0[q] + ar1[q] + redr[q][mt][lane] + brv;
        zreg[q] = 1.f / (1.f + expf(-pz));
        float rv = 1.f / (1.f + expf(-pr));
        pubP[mt][(((fcol >> 3) << 4) + kg * 4 + q) * 8 + (fcol & 7)] =
            f2bf(rv * hreg[q]);
      }
      asm volatile("s_waitcnt lgkmcnt(0)" ::: "memory");
      __builtin_amdgcn_sched_barrier(0);
      if (lane < 32) {
        short8 v = *(const short8*)(pubP[mt] + lane * 8);
        coh_store16(rhl + pubOff + lane * 8, v);
      }
      asm volatile("s_waitcnt vmcnt(0)" ::: "memory");
      if (lane == 0) coh_store_u32(selfP + blk, t + 1);
    }

    // ---- phase 2: optimistic gate + rh load + GEMM -----------------------
    {
      bool ready;
      {
        int f0 = aloadi(selfP + lane);
        ready = !__any(f0 < t + 1);
      }
      __builtin_amdgcn_sched_barrier(0);
      const float4v ag0s = ag0, ag1s = ag1;   // preserve x-side partial (kh=1)
      const u16* rbase = rhl + mt * 16384 + kh * 8192 + lane * 8;
      for (int a = 0; a < 2; ++a) {
        ag0 = ag0s; ag1 = ag1s;
#pragma unroll
        for (int k = 0; k < 16; ++k) cf[k] = coh16(rbase + k * 512);
#pragma unroll
        for (int k = 0; k < 16; ++k) {
          short8 vg = *(const short8*)(lG + (kh * 16 + k) * 512);
          if (k & 1) ag1 = MFMA16(cf[k], vg, ag1);
          else       ag0 = MFMA16(cf[k], vg, ag0);
        }
        if (ready) break;
        poll64(selfP, lane, t + 1);
        __builtin_amdgcn_sched_barrier(0);
        ready = true;
      }
    }
    if (kh == 1) {
#pragma unroll
      for (int q = 0; q < 4; ++q) redg[q][mt][lane] = ag0[q] + ag1[q];
    }
    __syncthreads();

    if (kh == 0) {
#pragma unroll
      for (int q = 0; q < 4; ++q) {
        float pg = ag0[q] + ag1[q] + redg[q][mt][lane] + bgv;
        float gv = tanhf(pg);
        float hn = zreg[q] * hreg[q] + (1.f - zreg[q]) * gv;
        hreg[q] = hn;
        pubP[mt][(((fcol >> 3) << 4) + kg * 4 + q) * 8 + (fcol & 7)] = f2bf(hn);
        if (t == SS - 1) hid[(crow0 + q) * (LL * HH) + grp * HH + colZ] = hn;
      }
      asm volatile("s_waitcnt lgkmcnt(0)" ::: "memory");
      __builtin_amdgcn_sched_barrier(0);
      if (lane < 32) {
        short8 v = *(const short8*)(pubP[mt] + lane * 8);
        coh_store16(ypkl + (size_t)wslot * 32768 + pubOff + lane * 8, v);
      }
      asm volatile("s_waitcnt vmcnt(0)" ::: "memory");
      if (lane == 0) coh_store_u32(selfD + blk, t + 1);
    }
  }
}

// layer_output[b,s,:] = y2[b][s][:] @ Wo^T + bo, A read in packed form
__launch_bounds__(64)
__global__ void out_gemm(const u16* __restrict__ ypk2, const u16* __restrict__ W,
                         const float* __restrict__ bo, float* __restrict__ C) {
  const int lane = threadIdx.x;
  const int nt4 = blockIdx.x & 15;
  const int sb = blockIdx.x >> 4;   // 0..1023
  const int s = sb >> 1, bt = sb & 1;
  const int n0 = nt4 * 64;
  const int fcol = lane & 15, kg = lane >> 4;
  const u16* Abase = ypk2 + (size_t)(s + 1) * 32768 + bt * 16384 + lane * 8;
  float4v acc[4];
#pragma unroll
  for (int j = 0; j < 4; ++j) acc[j] = (float4v){0, 0, 0, 0};

  for (int ks = 0; ks < 32; ++ks) {
    short8 a = *(const short8*)(Abase + ks * 512);
#pragma unroll
    for (int j = 0; j < 4; ++j) {
      short8 b = *(const short8*)(W + (size_t)(n0 + j * 16 + fcol) * HH + ks * 32 + kg * 8);
      acc[j] = MFMA16(a, b, acc[j]);
    }
  }
#pragma unroll
  for (int j = 0; j < 4; ++j)
#pragma unroll
    for (int q = 0; q < 4; ++q) {
      int b = bt * 16 + kg * 4 + q;
      int col = n0 + j * 16 + fcol;
      C[((size_t)b * SS + s) * OO + col] = acc[j][q] + bo[col];
    }
}

extern "C" void kernel_launch(void* const* d_in, const int* in_sizes, int n_in,
                              void* d_out, int out_size, void* d_ws, size_t ws_size,
                              hipStream_t stream) {
  (void)in_sizes; (void)n_in; (void)out_size; (void)ws_size;

  const float* x   = (const float*)d_in[0];
  const float* h0  = (const float*)d_in[1];
  const float* Wzx = (const float*)d_in[2];
  const float* bz  = (const float*)d_in[3];
  const float* Wzh = (const float*)d_in[4];
  const float* Wrx = (const float*)d_in[5];
  const float* br  = (const float*)d_in[6];
  const float* Wrh = (const float*)d_in[7];
  const float* Wgx = (const float*)d_in[8];
  const float* bg  = (const float*)d_in[9];
  const float* Wgh = (const float*)d_in[10];
  const float* Wo  = (const float*)d_in[11];
  const float* bo  = (const float*)d_in[12];
  float* out = (float*)d_out;

  // ws layout (~124 MB)
  u16* Pzh = (u16*)d_ws;
  u16* Pzx = Pzh + 3145728;
  u16* Prh = Pzx + 3145728;
  u16* Prx = Prh + 3145728;
  u16* Pgh = Prx + 3145728;
  u16* Pgx = Pgh + 3145728;
  u16* Wob = Pgx + 3145728;                 // 1M elems
  u16* xpk0 = Wob + 1048576;                // [512][32768]
  u16* ypk0 = xpk0 + 16777216;              // [128][32768] circular
  u16* ypk1 = ypk0 + 128 * 32768;           // [128][32768] circular
  u16* ypk2 = ypk1 + 128 * 32768;           // [513][32768]
  u16* rhA  = ypk2 + 513 * 32768;           // [3][32768]
  int* flagsD = (int*)(rhA + 3 * 32768);    // 5 groups x 128
  int* flagsP = flagsD + 640;               // 3 groups x 128

  hipMemsetAsync(flagsD, 0x7F, 128 * sizeof(int), stream);   // dummy producer
  hipMemsetAsync(flagsD + 128, 0, 512 * sizeof(int), stream);
  hipMemsetAsync(flagsP, 0, 384 * sizeof(int), stream);

  pack_w<<<3072, 256, 0, stream>>>(Wzh, Pzh, 3);
  pack_w<<<3072, 256, 0, stream>>>(Wzx, Pzx, 3);
  pack_w<<<3072, 256, 0, stream>>>(Wrh, Prh, 3);
  pack_w<<<3072, 256, 0, stream>>>(Wrx, Prx, 3);
  pack_w<<<3072, 256, 0, stream>>>(Wgh, Pgh, 3);
  pack_w<<<3072, 256, 0, stream>>>(Wgx, Pgx, 3);
  convert_bf16<<<256, 256, 0, stream>>>(Wo, Wob, 1048576);
  pack_x<<<4096, 256, 0, stream>>>(x, xpk0);
  pack_h0<<<384, 256, 0, stream>>>(h0, ypk0, ypk1, ypk2);

  gru_pipe<<<192, 256, 0, stream>>>(
      xpk0, ypk0, ypk1, ypk2,
      Pzh, Pzx, Prh, Prx, Pgh, Pgx,
      bz, br, bg, h0, rhA, out + 16777216, flagsD, flagsP);

  out_gemm<<<16384, 64, 0, stream>>>(ypk2, Wob, bo, out);
}

// Round 16
// 10116.457 us; speedup vs baseline: 3.4537x; 2.6011x over previous
//
#include <hip/hip_runtime.h>
#include <hip/hip_bf16.h>
#include <math.h>

// Multilayer GRU: B=32, S=512, H=1024, L=3, O=1024.
// v16: exact v12 structure (best: 16-col blocks, 64/layer, packed
// activations, LDS h-weights, unified h/y chain) with ONE change:
// per-mt flag banks. A wave of M-tile mt only reads rows of its own mt
// (h, rh, producer-y), so every gate polls its mt's 64 flags (1/lane,
// was 2/lane over 128 mixed) and the two independent 16-row recurrences
// decouple -- halves per-gate fan-in and skew tails.
// (v15's optimistic-execute duplicated GEMM bodies -> VGPR=256 + scratch
// spills, WRITE 5.8GB. No code duplication here.)

#define BB 32
#define SS 512
#define HH 1024
#define LL 3
#define OO 1024
#define SH (SS*HH)

typedef __attribute__((ext_vector_type(8))) short short8;
typedef __attribute__((ext_vector_type(4))) float float4v;
typedef unsigned long long u64;
typedef unsigned int u32;
typedef unsigned short u16;

__device__ __forceinline__ u16 f2bf(float f) {
  union { float f; u32 u; } v; v.f = f;
  return (u16)((v.u + 0x7FFFu + ((v.u >> 16) & 1u)) >> 16);
}

__global__ void convert_bf16(const float* __restrict__ src,
                             u16* __restrict__ dst, int n) {
  int stride = gridDim.x * blockDim.x;
  for (int i = blockIdx.x * blockDim.x + threadIdx.x; i < n; i += stride)
    dst[i] = f2bf(src[i]);
}

// Pack W[nmat][1024][1024] into MFMA B-fragment stream
__global__ void pack_w(const float* __restrict__ src, u16* __restrict__ dst,
                       int nmat) {
  int stride = gridDim.x * blockDim.x;
  int total = nmat * 1048576;
  for (int i = blockIdx.x * blockDim.x + threadIdx.x; i < total; i += stride) {
    int m = i >> 20, e = i & 1048575;
    int row = e >> 10, k = e & 1023;
    int lane = ((k >> 3) & 3) * 16 + (row & 15);
    int di = ((row >> 4) * 32 + (k >> 5)) * 512 + lane * 8 + (k & 7);
    dst[m * 1048576 + di] = f2bf(src[i]);
  }
}

// x[B,S,H] fp32 -> packed per-t activation tiles
__global__ void pack_x(const float* __restrict__ x, u16* __restrict__ dst) {
  int stride = gridDim.x * blockDim.x;
  for (int d = blockIdx.x * blockDim.x + threadIdx.x; d < SS * 32768; d += stride) {
    int t = d >> 15, e = d & 32767;
    int rt = e >> 14, ks = (e >> 9) & 31, lane = (e >> 3) & 63, j = e & 7;
    int b = rt * 16 + (lane & 15), c = ks * 32 + ((lane >> 4) << 3) + j;
    dst[d] = f2bf(x[(size_t)b * SH + (size_t)t * HH + c]);
  }
}

// h0[B, L, H] fp32 -> slot 0 of each layer chain (packed)
__global__ void pack_h0(const float* __restrict__ h0, u16* __restrict__ y0,
                        u16* __restrict__ y1, u16* __restrict__ y2) {
  int i = blockIdx.x * 256 + threadIdx.x;   // 98304
  int l = i >> 15, e = i & 32767;
  int rt = e >> 14, ks = (e >> 9) & 31, lane = (e >> 3) & 63, j = e & 7;
  int b = rt * 16 + (lane & 15), c = ks * 32 + ((lane >> 4) << 3) + j;
  u16 v = f2bf(h0[b * (LL * HH) + l * HH + c]);
  u16* dst = (l == 0) ? y0 : ((l == 1) ? y1 : y2);
  dst[e] = v;
}

// ---- access primitives ----------------------------------------------------
__device__ __forceinline__ short8 coh16(const u16* p) {
  const u64* q = (const u64*)p;
  union { u64 q[2]; short8 v; } u;
  u.q[0] = __hip_atomic_load(q,     __ATOMIC_RELAXED, __HIP_MEMORY_SCOPE_AGENT);
  u.q[1] = __hip_atomic_load(q + 1, __ATOMIC_RELAXED, __HIP_MEMORY_SCOPE_AGENT);
  return u.v;
}
__device__ __forceinline__ void coh_store16(u16* p, short8 v) {
  asm volatile("global_store_dwordx4 %0, %1, off sc0 sc1"
               :: "v"(p), "v"(v) : "memory");
}
__device__ __forceinline__ void coh_store_u32(int* p, int v) {
  asm volatile("global_store_dword %0, %1, off sc0 sc1"
               :: "v"(p), "v"(v) : "memory");
}
// poll 64 flags (1/lane) until all >= tgt
__device__ __forceinline__ void poll64(const int* base, int lane, int tgt) {
  int f = __hip_atomic_load(base + lane, __ATOMIC_RELAXED,
                            __HIP_MEMORY_SCOPE_AGENT);
  while (__any(f < tgt)) {
    __builtin_amdgcn_s_sleep(1);
    f = __hip_atomic_load(base + lane, __ATOMIC_RELAXED,
                          __HIP_MEMORY_SCOPE_AGENT);
  }
}

#define MFMA16(a, b, c) __builtin_amdgcn_mfma_f32_16x16x32_bf16(a, b, c, 0, 0, 0)

__launch_bounds__(256, 1)
__global__ void gru_pipe(
    const u16* __restrict__ xpk0,
    u16* __restrict__ ypk0, u16* __restrict__ ypk1, u16* __restrict__ ypk2,
    const u16* __restrict__ Pzh, const u16* __restrict__ Pzx,
    const u16* __restrict__ Prh, const u16* __restrict__ Prx,
    const u16* __restrict__ Pgh, const u16* __restrict__ Pgx,
    const float* __restrict__ bz, const float* __restrict__ br,
    const float* __restrict__ bg, const float* __restrict__ h0,
    u16* __restrict__ rhA, float* __restrict__ hid,
    int* __restrict__ flagsD, int* __restrict__ flagsP) {
  __shared__ __align__(16) u16 smW[3][16384];     // Wzh, Wrh, Wgh (96 KB)
  __shared__ float redz[4][2][64], redr[4][2][64], redg[4][2][64];
  __shared__ __align__(16) u16 pubP[2][256];      // per-mt packed publish buf

  const int grp = blockIdx.x >> 6;        // layer 0..2
  const int blk = blockIdx.x & 63;        // 16-col tile
  const int tid = threadIdx.x;
  const int lane = tid & 63;
  const int wave = tid >> 6;
  const int mt = wave & 1;                // M-tile: rows 0-15 / 16-31
  const int kh = wave >> 1;               // phase1 side: 0=h, 1=x
  const int fcol = lane & 15, kg = lane >> 4;
  const int crow0 = mt * 16 + kg * 4;
  const int colZ = blk * 16 + fcol;

  u16* ypkl       = (grp == 0) ? ypk0 : ((grp == 1) ? ypk1 : ypk2);
  const u16* ypkp = (grp == 1) ? ypk0 : ypk1;
  const bool circ = (grp < 2);
  const size_t lw = (size_t)grp * 1048576;
  const u16* wZx = Pzx + lw + blk * 16384 + lane * 8;
  const u16* wRx = Prx + lw + blk * 16384 + lane * 8;
  const u16* wGx = Pgx + lw + blk * 16384 + lane * 8;
  u16* rhl = rhA + grp * 32768;
  // per-mt flag banks: [group][mt][blk]
  int* selfD = flagsD + (grp + 1) * 128 + mt * 64;
  int* prodD = flagsD + grp * 128 + mt * 64;
  int* consD = flagsD + (grp + 2) * 128 + mt * 64;  // valid only grp<2
  int* selfP = flagsP + grp * 128 + mt * 64;

  // ---- stage h-side weight slices into LDS (once) -------------------------
  {
    const u64* g0 = (const u64*)(Pzh + lw + blk * 16384);
    const u64* g1 = (const u64*)(Prh + lw + blk * 16384);
    const u64* g2 = (const u64*)(Pgh + lw + blk * 16384);
    u64* d0 = (u64*)smW[0];
    u64* d1 = (u64*)smW[1];
    u64* d2 = (u64*)smW[2];
#pragma unroll
    for (int j = 0; j < 16; ++j) {
      d0[j * 256 + tid] = g0[j * 256 + tid];
      d1[j * 256 + tid] = g1[j * 256 + tid];
      d2[j * 256 + tid] = g2[j * 256 + tid];
    }
  }
  __syncthreads();
  const u16* lZ = smW[0] + lane * 8;
  const u16* lR = smW[1] + lane * 8;
  const u16* lG = smW[2] + lane * 8;

  float hreg[4] = {0, 0, 0, 0}, zreg[4] = {0, 0, 0, 0};
  float bzv = 0, brv = 0, bgv = 0;
  if (kh == 0) {
#pragma unroll
    for (int q = 0; q < 4; ++q)
      hreg[q] = h0[(crow0 + q) * (LL * HH) + grp * HH + colZ];
    bzv = bz[grp * HH + colZ];
    brv = br[grp * HH + colZ];
    bgv = bg[grp * HH + colZ];
  }

  // publish target within a packed 32-col tile (block owns a 16-col half)
  const int pubOff = (mt * 32 + (blk >> 1)) * 512 + (blk & 1) * 256;

  for (int t = 0; t < SS; ++t) {
    const int hslot = circ ? (t & 127) : t;
    const int wslot = circ ? ((t + 1) & 127) : (t + 1);

    // ---- phase-1 gate (per-wave, per-mt) ---------------------------------
    if (kh == 0) {
      poll64(selfD, lane, t);                         // own-layer mt-half RAW
      if (circ && t >= 128) poll64(consD, lane, t - 127);  // chain WAR
    } else if (grp != 0) {
      poll64(prodD, lane, t + 1);                     // producer mt-half y[t]
    }

    float4v az0 = {0,0,0,0}, az1 = {0,0,0,0};
    float4v ar0 = {0,0,0,0}, ar1 = {0,0,0,0};
    float4v ag0 = {0,0,0,0}, ag1 = {0,0,0,0};
    short8 cf[16];

    if (kh == 0) {
      // ---- h-side z,r GEMM: A packed-coherent, B from LDS ----
      const u16* hbase = ypkl + (size_t)hslot * 32768 + mt * 16384 + lane * 8;
#pragma unroll
      for (int c0 = 0; c0 < 32; c0 += 16) {
#pragma unroll
        for (int k = 0; k < 16; ++k)
          cf[k] = coh16(hbase + (c0 + k) * 512);
#pragma unroll
        for (int k = 0; k < 16; ++k) {
          short8 vz = *(const short8*)(lZ + (c0 + k) * 512);
          short8 vr = *(const short8*)(lR + (c0 + k) * 512);
          if (k & 1) { az1 = MFMA16(cf[k], vz, az1); ar1 = MFMA16(cf[k], vr, ar1); }
          else       { az0 = MFMA16(cf[k], vz, az0); ar0 = MFMA16(cf[k], vr, ar0); }
        }
      }
    } else {
      // ---- x-side z,r (+gx) GEMM: A packed, B streamed ----
      const u16* xbase = (grp == 0)
          ? (xpk0 + (size_t)t * 32768 + mt * 16384 + lane * 8)
          : (ypkp + (size_t)((t + 1) & 127) * 32768 + mt * 16384 + lane * 8);
#pragma unroll
      for (int c0 = 0; c0 < 32; c0 += 16) {
        if (grp != 0) {
#pragma unroll
          for (int k = 0; k < 16; ++k) cf[k] = coh16(xbase + (c0 + k) * 512);
        } else {
#pragma unroll
          for (int k = 0; k < 16; ++k) cf[k] = *(const short8*)(xbase + (c0 + k) * 512);
        }
#pragma unroll
        for (int k = 0; k < 16; ++k) {
          int ks = c0 + k;
          short8 vz = *(const short8*)(wZx + ks * 512);
          short8 vr = *(const short8*)(wRx + ks * 512);
          short8 vg = *(const short8*)(wGx + ks * 512);
          if (k & 1) { az1 = MFMA16(cf[k], vz, az1); ar1 = MFMA16(cf[k], vr, ar1);
                       ag1 = MFMA16(cf[k], vg, ag1); }
          else       { az0 = MFMA16(cf[k], vz, az0); ar0 = MFMA16(cf[k], vr, ar0);
                       ag0 = MFMA16(cf[k], vg, ag0); }
        }
      }
#pragma unroll
      for (int q = 0; q < 4; ++q) {
        redz[q][mt][lane] = az0[q] + az1[q];
        redr[q][mt][lane] = ar0[q] + ar1[q];
      }
    }
    __syncthreads();

    if (kh == 0) {
      // finalize z,r; packed-publish r*h (one dwordx4/lane over 32 lanes)
#pragma unroll
      for (int q = 0; q < 4; ++q) {
        float pz = az0[q] + az1[q] + redz[q][mt][lane] + bzv;
        float pr = ar0[q] + ar1[q] + redr[q][mt][lane] + brv;
        zreg[q] = 1.f / (1.f + expf(-pz));
        float rv = 1.f / (1.f + expf(-pr));
        pubP[mt][(((fcol >> 3) << 4) + kg * 4 + q) * 8 + (fcol & 7)] =
            f2bf(rv * hreg[q]);
      }
      asm volatile("s_waitcnt lgkmcnt(0)" ::: "memory");
      __builtin_amdgcn_sched_barrier(0);
      if (lane < 32) {
        short8 v = *(const short8*)(pubP[mt] + lane * 8);
        coh_store16(rhl + pubOff + lane * 8, v);
      }
      asm volatile("s_waitcnt vmcnt(0)" ::: "memory");
      if (lane == 0) coh_store_u32(selfP + blk, t + 1);
    }

    // ---- phase-2 gate: rh rows of own mt published -----------------------
    poll64(selfP, lane, t + 1);

    // rh frags (packed): 16 chunks per wave (K split by kh)
    {
      const u16* rbase = rhl + mt * 16384 + kh * 8192 + lane * 8;
#pragma unroll
      for (int k = 0; k < 16; ++k) cf[k] = coh16(rbase + k * 512);
#pragma unroll
      for (int k = 0; k < 16; ++k) {
        short8 vg = *(const short8*)(lG + (kh * 16 + k) * 512);
        if (k & 1) ag1 = MFMA16(cf[k], vg, ag1);
        else       ag0 = MFMA16(cf[k], vg, ag0);
      }
    }
    if (kh == 1) {
#pragma unroll
      for (int q = 0; q < 4; ++q) redg[q][mt][lane] = ag0[q] + ag1[q];
    }
    __syncthreads();

    if (kh == 0) {
#pragma unroll
      for (int q = 0; q < 4; ++q) {
        float pg = ag0[q] + ag1[q] + redg[q][mt][lane] + bgv;
        float gv = tanhf(pg);
        float hn = zreg[q] * hreg[q] + (1.f - zreg[q]) * gv;
        hreg[q] = hn;
        pubP[mt][(((fcol >> 3) << 4) + kg * 4 + q) * 8 + (fcol & 7)] = f2bf(hn);
        if (t == SS - 1) hid[(crow0 + q) * (LL * HH) + grp * HH + colZ] = hn;
      }
      asm volatile("s_waitcnt lgkmcnt(0)" ::: "memory");
      __builtin_amdgcn_sched_barrier(0);
      if (lane < 32) {
        short8 v = *(const short8*)(pubP[mt] + lane * 8);
        coh_store16(ypkl + (size_t)wslot * 32768 + pubOff + lane * 8, v);
      }
      asm volatile("s_waitcnt vmcnt(0)" ::: "memory");
      if (lane == 0) coh_store_u32(selfD + blk, t + 1);
    }
  }
}

// layer_output[b,s,:] = y2[b][s][:] @ Wo^T + bo, A read in packed form
__launch_bounds__(64)
__global__ void out_gemm(const u16* __restrict__ ypk2, const u16* __restrict__ W,
                         const float* __restrict__ bo, float* __restrict__ C) {
  const int lane = threadIdx.x;
  const int nt4 = blockIdx.x & 15;
  const int sb = blockIdx.x >> 4;   // 0..1023
  const int s = sb >> 1, bt = sb & 1;
  const int n0 = nt4 * 64;
  const int fcol = lane & 15, kg = lane >> 4;
  const u16* Abase = ypk2 + (size_t)(s + 1) * 32768 + bt * 16384 + lane * 8;
  float4v acc[4];
#pragma unroll
  for (int j = 0; j < 4; ++j) acc[j] = (float4v){0, 0, 0, 0};

  for (int ks = 0; ks < 32; ++ks) {
    short8 a = *(const short8*)(Abase + ks * 512);
#pragma unroll
    for (int j = 0; j < 4; ++j) {
      short8 b = *(const short8*)(W + (size_t)(n0 + j * 16 + fcol) * HH + ks * 32 + kg * 8);
      acc[j] = MFMA16(a, b, acc[j]);
    }
  }
#pragma unroll
  for (int j = 0; j < 4; ++j)
#pragma unroll
    for (int q = 0; q < 4; ++q) {
      int b = bt * 16 + kg * 4 + q;
      int col = n0 + j * 16 + fcol;
      C[((size_t)b * SS + s) * OO + col] = acc[j][q] + bo[col];
    }
}

extern "C" void kernel_launch(void* const* d_in, const int* in_sizes, int n_in,
                              void* d_out, int out_size, void* d_ws, size_t ws_size,
                              hipStream_t stream) {
  (void)in_sizes; (void)n_in; (void)out_size; (void)ws_size;

  const float* x   = (const float*)d_in[0];
  const float* h0  = (const float*)d_in[1];
  const float* Wzx = (const float*)d_in[2];
  const float* bz  = (const float*)d_in[3];
  const float* Wzh = (const float*)d_in[4];
  const float* Wrx = (const float*)d_in[5];
  const float* br  = (const float*)d_in[6];
  const float* Wrh = (const float*)d_in[7];
  const float* Wgx = (const float*)d_in[8];
  const float* bg  = (const float*)d_in[9];
  const float* Wgh = (const float*)d_in[10];
  const float* Wo  = (const float*)d_in[11];
  const float* bo  = (const float*)d_in[12];
  float* out = (float*)d_out;

  // ws layout (~124 MB)
  u16* Pzh = (u16*)d_ws;
  u16* Pzx = Pzh + 3145728;
  u16* Prh = Pzx + 3145728;
  u16* Prx = Prh + 3145728;
  u16* Pgh = Prx + 3145728;
  u16* Pgx = Pgh + 3145728;
  u16* Wob = Pgx + 3145728;                 // 1M elems
  u16* xpk0 = Wob + 1048576;                // [512][32768]
  u16* ypk0 = xpk0 + 16777216;              // [128][32768] circular
  u16* ypk1 = ypk0 + 128 * 32768;           // [128][32768] circular
  u16* ypk2 = ypk1 + 128 * 32768;           // [513][32768]
  u16* rhA  = ypk2 + 513 * 32768;           // [3][32768]
  int* flagsD = (int*)(rhA + 3 * 32768);    // 5 groups x 128 (per-mt banks)
  int* flagsP = flagsD + 640;               // 3 groups x 128

  hipMemsetAsync(flagsD, 0x7F, 128 * sizeof(int), stream);   // dummy producer
  hipMemsetAsync(flagsD + 128, 0, 512 * sizeof(int), stream);
  hipMemsetAsync(flagsP, 0, 384 * sizeof(int), stream);

  pack_w<<<3072, 256, 0, stream>>>(Wzh, Pzh, 3);
  pack_w<<<3072, 256, 0, stream>>>(Wzx, Pzx, 3);
  pack_w<<<3072, 256, 0, stream>>>(Wrh, Prh, 3);
  pack_w<<<3072, 256, 0, stream>>>(Wrx, Prx, 3);
  pack_w<<<3072, 256, 0, stream>>>(Wgh, Pgh, 3);
  pack_w<<<3072, 256, 0, stream>>>(Wgx, Pgx, 3);
  convert_bf16<<<256, 256, 0, stream>>>(Wo, Wob, 1048576);
  pack_x<<<4096, 256, 0, stream>>>(x, xpk0);
  pack_h0<<<384, 256, 0, stream>>>(h0, ypk0, ypk1, ypk2);

  gru_pipe<<<192, 256, 0, stream>>>(
      xpk0, ypk0, ypk1, ypk2,
      Pzh, Pzx, Prh, Prx, Pgh, Pgx,
      bz, br, bg, h0, rhA, out + 16777216, flagsD, flagsP);

  out_gemm<<<16384, 64, 0, stream>>>(ypk2, Wob, bo, out);
}